// Round 6
// baseline (1073.463 us; speedup 1.0000x reference)
//
#include <hip/hip_runtime.h>
#include <cstdint>
#include <cstddef>

// Problem constants
#define NBATCH 128
#define NTIME  512
#define NIN    64
#define NHID   256
#define NG     768     // 3*H
#define NLAT   32
#define NPp    16      // P
#define NPI    48
#define NOD    8
#define NPAR   1056
#define MEAN_OFF 0
#define STD_OFF  524288      // B*T*OD
#define HT_OFF   1048576     // 2*B*T*OD

typedef _Float16 f16;
typedef _Float16 f16x2 __attribute__((ext_vector_type(2)));
typedef uint32_t u32;

static __device__ __forceinline__ f16x2 u2h(u32 u) {
  union { u32 u; f16x2 h; } x; x.u = u; return x.h;
}
static __device__ __forceinline__ u32 pkf(float a, float b) {
  union { f16x2 h; u32 u; } r; r.h = f16x2{(f16)a, (f16)b}; return r.u;
}
static __device__ __forceinline__ uint4 pack8(float4 a, float4 b) {
  uint4 r;
  r.x = pkf(a.x, a.y); r.y = pkf(a.z, a.w);
  r.z = pkf(b.x, b.y); r.w = pkf(b.z, b.w);
  return r;
}

static __device__ __forceinline__ float fdot2(f16x2 a, f16x2 b, float c) {
#if __has_builtin(__builtin_amdgcn_fdot2)
  return __builtin_amdgcn_fdot2(a, b, c, false);   // v_dot2_f32_f16
#else
  return c + (float)a.x * (float)b.x + (float)a.y * (float)b.y;
#endif
}
static __device__ __forceinline__ float fexp2(float x) {
#if __has_builtin(__builtin_amdgcn_exp2f)
  return __builtin_amdgcn_exp2f(x);
#else
  return exp2f(x);
#endif
}
static __device__ __forceinline__ float frcp(float x) {
#if __has_builtin(__builtin_amdgcn_rcpf)
  return __builtin_amdgcn_rcpf(x);
#else
  return 1.0f / x;
#endif
}
static __device__ __forceinline__ float fsigmoid(float x) {
  return frcp(1.0f + fexp2(-1.4426950408889634f * x));
}
static __device__ __forceinline__ float ftanh(float x) {
  return 1.0f - 2.0f * frcp(1.0f + fexp2(2.8853900817779268f * x));
}
static __device__ __forceinline__ float fexpf_(float x) {
  return fexp2(1.4426950408889634f * x);
}

// ---------------------------------------------------------------------------
// K1: gx[m, n] = sum_k x[m,k] * w_ih[n,k] + b_ih[n]   (M=65536, N=768, K=64)
// ---------------------------------------------------------------------------
__global__ __launch_bounds__(256, 4) void k_gx(
    const float* __restrict__ x, const float* __restrict__ w_ih,
    const float* __restrict__ b_ih, f16* __restrict__ gx)
{
  __shared__ f16x2 xs[64 * 33];
  __shared__ f16x2 ws[192 * 33];
  __shared__ float bs[192];
  const int tid = threadIdx.x;
  const int m0 = blockIdx.x * 64;
  const int c0 = blockIdx.y * 192;
  const float2* x2 = (const float2*)x;
  const float2* w2 = (const float2*)w_ih;
  for (int idx = tid; idx < 64 * 32; idx += 256) {
    int r = idx >> 5, kk = idx & 31;
    float2 v = x2[(size_t)(m0 + r) * 32 + kk];
    xs[r * 33 + kk] = f16x2{(f16)v.x, (f16)v.y};
  }
  for (int idx = tid; idx < 192 * 32; idx += 256) {
    int r = idx >> 5, kk = idx & 31;
    float2 v = w2[(size_t)(c0 + r) * 32 + kk];
    ws[r * 33 + kk] = f16x2{(f16)v.x, (f16)v.y};
  }
  if (tid < 192) bs[tid] = b_ih[c0 + tid];
  __syncthreads();

  const int tc = tid & 15;
  const int tr = tid >> 4;
  float acc[4][12];
  #pragma unroll
  for (int j = 0; j < 4; ++j)
    #pragma unroll
    for (int i = 0; i < 12; ++i) acc[j][i] = 0.f;

  for (int kk = 0; kk < 32; ++kk) {
    f16x2 xa[4], wb[12];
    #pragma unroll
    for (int j = 0; j < 4; ++j) xa[j] = xs[(tr * 4 + j) * 33 + kk];
    #pragma unroll
    for (int i = 0; i < 12; ++i) wb[i] = ws[(tc * 12 + i) * 33 + kk];
    #pragma unroll
    for (int j = 0; j < 4; ++j)
      #pragma unroll
      for (int i = 0; i < 12; ++i) acc[j][i] = fdot2(xa[j], wb[i], acc[j][i]);
  }

  f16x2* g2 = (f16x2*)gx;
  #pragma unroll
  for (int j = 0; j < 4; ++j) {
    size_t row = (size_t)(m0 + tr * 4 + j);
    #pragma unroll
    for (int i2 = 0; i2 < 6; ++i2) {
      float a0 = acc[j][2 * i2]     + bs[tc * 12 + 2 * i2];
      float a1 = acc[j][2 * i2 + 1] + bs[tc * 12 + 2 * i2 + 1];
      g2[row * 384 + (size_t)(c0 / 2) + tc * 6 + i2] = f16x2{(f16)a0, (f16)a1};
    }
  }
}

// ---------------------------------------------------------------------------
// K2 v7: GRU scan. Root cause of the invariant ~620-700 us across R1-R5:
// the per-thread weight ARRAY was never promoted out of its alloca ->
// lived in scratch -> 50 MB spill (visible as WRITE_SIZE excess) re-read
// every step at the cache-hierarchy ceiling. Fix: 24 NAMED uint4 locals
// (96 VGPRs of packed f16x2) -- SSA values, no alloca, allocator must use
// registers. 1024 thr/block, (1024,4) -> 128-reg budget, peak live ~124.
// Thread (kq = tid>>8 wave-uniform, u = tid&255) owns rows {u,256+u,512+u}
// x K-quarter. h via same-address b128 LDS broadcasts; stride-1 parts;
// gates on tid<256.
// ---------------------------------------------------------------------------
#define LDG(W0,W1,W2,W3,W4,W5,W6,W7, r) { \
    const float4* p4 = (const float4*)(w_hh + (size_t)(r) * 256 + kq * 64); \
    float4 t0 = p4[0], t1 = p4[1];  W0 = pack8(t0, t1); \
    float4 t2 = p4[2], t3 = p4[3];  W1 = pack8(t2, t3); \
    float4 t4 = p4[4], t5 = p4[5];  W2 = pack8(t4, t5); \
    float4 t6 = p4[6], t7 = p4[7];  W3 = pack8(t6, t7); \
    float4 t8 = p4[8], t9 = p4[9];  W4 = pack8(t8, t9); \
    float4 ta = p4[10], tb = p4[11]; W5 = pack8(ta, tb); \
    float4 tc_ = p4[12], td = p4[13]; W6 = pack8(tc_, td); \
    float4 te_ = p4[14], tf = p4[15]; W7 = pack8(te_, tf); }

#define STEPC4(Ri, Zi, Ni, i) { \
    uint4 hv = hb[i]; \
    f16x2 h0 = u2h(hv.x), h1 = u2h(hv.y), h2v = u2h(hv.z), h3 = u2h(hv.w); \
    a0 = fdot2(u2h(Ri.x), h0, a0); b0 = fdot2(u2h(Zi.x), h0, b0); d0 = fdot2(u2h(Ni.x), h0, d0); \
    a1 = fdot2(u2h(Ri.y), h1, a1); b1 = fdot2(u2h(Zi.y), h1, b1); d1 = fdot2(u2h(Ni.y), h1, d1); \
    a0 = fdot2(u2h(Ri.z), h2v, a0); b0 = fdot2(u2h(Zi.z), h2v, b0); d0 = fdot2(u2h(Ni.z), h2v, d0); \
    a1 = fdot2(u2h(Ri.w), h3, a1); b1 = fdot2(u2h(Zi.w), h3, b1); d1 = fdot2(u2h(Ni.w), h3, d1); }

__global__ __launch_bounds__(1024, 4) void k_scan(
    const float* __restrict__ hidden, const float* __restrict__ w_hh,
    const float* __restrict__ b_hh, const f16* __restrict__ gx,
    f16* __restrict__ rnn, float* __restrict__ out)
{
  __shared__ __align__(16) f16x2 hbuf[2][128];   // double-buffered h (f16)
  __shared__ float parts[4 * 768];               // [kq][row] partial sums
  const int tid = threadIdx.x;
  const int b = blockIdx.x;
  const int kq = tid >> 8;       // 0..3, wave-uniform
  const int u  = tid & 255;

  // --- stationary weights: 24 named uint4 (SSA -> registers, no alloca)
  uint4 R0, R1, R2, R3, R4, R5, R6, R7;
  uint4 Z0, Z1, Z2, Z3, Z4, Z5, Z6, Z7;
  uint4 N0, N1, N2, N3, N4, N5, N6, N7;
  LDG(R0,R1,R2,R3,R4,R5,R6,R7, u);
  LDG(Z0,Z1,Z2,Z3,Z4,Z5,Z6,Z7, 256 + u);
  LDG(N0,N1,N2,N3,N4,N5,N6,N7, 512 + u);

  // --- gate-thread state (tid < 256 owns unit u = tid)
  float br = 0.f, bz = 0.f, bn = 0.f, hprev = 0.f;
  f16 c_r = 0, c_z = 0, c_n = 0;
  const f16* gp = gx + (size_t)b * NTIME * NG;
  if (tid < 256) {
    br = b_hh[u]; bz = b_hh[256 + u]; bn = b_hh[512 + u];
    hprev = hidden[b * 256 + u];
    ((f16*)hbuf[0])[u] = (f16)hprev;
    c_r = gp[u]; c_z = gp[256 + u]; c_n = gp[512 + u];
  }
  f16* rnn_p = rnn + (size_t)b * NTIME * NHID + u;   // used only if tid<256
  __syncthreads();

  for (int t = 0; t < NTIME; ++t) {
    // prefetch gx for t+1 (in flight across the whole step)
    f16 q_r = 0, q_z = 0, q_n = 0;
    if (tid < 256) {
      const int tp = (t + 1 < NTIME) ? (t + 1) : (NTIME - 1);
      const f16* gq = gp + (size_t)tp * NG;
      q_r = gq[u]; q_z = gq[256 + u]; q_n = gq[512 + u];
    }

    // --- phase A: 96 dot2 per thread; h via same-address b128 broadcasts
    const uint4* hb = (const uint4*)(&hbuf[t & 1][kq * 32]);
    float a0 = 0.f, a1 = 0.f, b0 = 0.f, b1 = 0.f, d0 = 0.f, d1 = 0.f;
    STEPC4(R0, Z0, N0, 0)
    STEPC4(R1, Z1, N1, 1)
    STEPC4(R2, Z2, N2, 2)
    STEPC4(R3, Z3, N3, 3)
    STEPC4(R4, Z4, N4, 4)
    STEPC4(R5, Z5, N5, 5)
    STEPC4(R6, Z6, N6, 6)
    STEPC4(R7, Z7, N7, 7)
    {
      float* pp = parts + kq * 768 + u;   // stride-1 across lanes
      pp[0]   = a0 + a1;
      pp[256] = b0 + b1;
      pp[512] = d0 + d1;
    }
    __syncthreads();

    // --- phase B: gates on threads 0..255 (kq == 0)
    if (tid < 256) {
      float gr = br + (float)c_r;
      float gz = bz + (float)c_z;
      float hn = bn;
      #pragma unroll
      for (int kk = 0; kk < 4; ++kk) {
        gr += parts[kk * 768 + u];
        gz += parts[kk * 768 + 256 + u];
        hn += parts[kk * 768 + 512 + u];
      }
      float r_ = fsigmoid(gr);
      float z_ = fsigmoid(gz);
      float n_ = ftanh((float)c_n + r_ * hn);
      hprev = (1.0f - z_) * n_ + z_ * hprev;
      ((f16*)hbuf[(t + 1) & 1])[u] = (f16)hprev;
      rnn_p[(size_t)t * NHID] = (f16)hprev;
      c_r = q_r; c_z = q_z; c_n = q_n;
    }
    __syncthreads();
  }
  if (tid < 256) out[HT_OFF + b * 256 + u] = hprev;
}

// ---------------------------------------------------------------------------
// K3 helper: half-row dot (16 of 32 latents; caller pre-offset wb by kh*2
// uint4 and t8 = te2 + kh*8). init carries b_par[row] on kh==0 only.
// ---------------------------------------------------------------------------
static __device__ __forceinline__ float rowdot_h(const uint4* __restrict__ wb,
                                                 const f16x2* __restrict__ t8,
                                                 int r, float init)
{
  uint4 v0 = wb[r * 4];
  uint4 v1 = wb[r * 4 + 1];
  float a0 = init, a1 = 0.f, a2 = 0.f, a3 = 0.f;
  a0 = fdot2(u2h(v0.x), t8[0], a0);
  a1 = fdot2(u2h(v0.y), t8[1], a1);
  a2 = fdot2(u2h(v0.z), t8[2], a2);
  a3 = fdot2(u2h(v0.w), t8[3], a3);
  a0 = fdot2(u2h(v1.x), t8[4], a0);
  a1 = fdot2(u2h(v1.y), t8[5], a1);
  a2 = fdot2(u2h(v1.z), t8[6], a2);
  a3 = fdot2(u2h(v1.w), t8[7], a3);
  return (a0 + a1) + (a2 + a3);
}

// ---------------------------------------------------------------------------
// K3 v4: head, 2 threads per (b,t) row (kh = K-half) -> 2048 waves = 2/SIMD.
// launch_bounds(256,4) pins a 128-reg budget so te[32]/vh/oh stay resident
// (default occupancy target would squeeze them into ~64 regs -> spill).
// ---------------------------------------------------------------------------
#define HEAD_T 256
__global__ __launch_bounds__(HEAD_T, 4) void k_head(
    const float* __restrict__ x, const float* __restrict__ w_lat,
    const float* __restrict__ b_lat, const float* __restrict__ w_par,
    const float* __restrict__ b_par, const f16* __restrict__ rnn,
    float* __restrict__ out)
{
  __shared__ __align__(16) f16x2 buf[384 * 16];   // 24 KB chunk buffer
  const int tid = threadIdx.x;
  const int j = tid >> 1, kh = tid & 1;
  const size_t m = (size_t)blockIdx.x * (HEAD_T / 2) + j;

  // ---- phase A: te = b_lat + w_lat @ h  (K split by kh)
  const float2* wl2 = (const float2*)w_lat;
  for (int idx = tid; idx < 32 * 128; idx += HEAD_T) {
    float2 v = wl2[idx];
    buf[idx] = f16x2{(f16)v.x, (f16)v.y};
  }
  __syncthreads();

  float te[32];
  #pragma unroll
  for (int c = 0; c < 32; ++c) te[c] = kh ? 0.f : b_lat[c];
  const uint4* hrow = (const uint4*)(rnn + m * NHID) + kh * 16;
  const uint4* wl4 = (const uint4*)buf;    // 32 uint4 per 256-wide row
  #pragma unroll 2
  for (int c4 = 0; c4 < 16; ++c4) {
    uint4 hv = hrow[c4];
    f16x2 hx0 = u2h(hv.x), hx1 = u2h(hv.y), hx2 = u2h(hv.z), hx3 = u2h(hv.w);
    #pragma unroll
    for (int c = 0; c < 32; ++c) {
      uint4 wv = wl4[c * 32 + kh * 16 + c4];
      te[c] = fdot2(u2h(wv.x), hx0, te[c]);
      te[c] = fdot2(u2h(wv.y), hx1, te[c]);
      te[c] = fdot2(u2h(wv.z), hx2, te[c]);
      te[c] = fdot2(u2h(wv.w), hx3, te[c]);
    }
  }
  #pragma unroll
  for (int c = 0; c < 32; ++c) te[c] += __shfl_xor(te[c], 1, 64);
  f16x2 te2[16];
  #pragma unroll
  for (int k = 0; k < 16; ++k) te2[k] = f16x2{(f16)te[2 * k], (f16)te[2 * k + 1]};
  const f16x2* t8 = te2 + kh * 8;
  __syncthreads();

  const float2* wp2 = (const float2*)w_par;   // 16 float2 per 32-wide row
  const uint4* wb = ((const uint4*)buf) + kh * 2;
  const float* xrow = x + m * NIN;
  float vh[16];
  #pragma unroll
  for (int p = 0; p < 16; ++p) vh[p] = 0.f;

  // ---- phase B0: w_h rows [0,384)  (p = 0..7)
  for (int idx = tid; idx < 384 * 16; idx += HEAD_T) {
    float2 v = wp2[idx];
    buf[idx] = f16x2{(f16)v.x, (f16)v.y};
  }
  __syncthreads();
  for (int i = 0; i < NPI; ++i) {
    float xi = xrow[i];
    #pragma unroll
    for (int p = 0; p < 8; ++p) {
      int row = p * NPI + i;
      float wv = rowdot_h(wb, t8, row, kh ? 0.f : b_par[row]);
      vh[p] += wv * xi;
    }
  }
  __syncthreads();

  // ---- phase B1: w_h rows [384,768)  (p = 8..15)
  for (int idx = tid; idx < 384 * 16; idx += HEAD_T) {
    float2 v = wp2[384 * 16 + idx];
    buf[idx] = f16x2{(f16)v.x, (f16)v.y};
  }
  __syncthreads();
  for (int i = 0; i < NPI; ++i) {
    float xi = xrow[i];
    #pragma unroll
    for (int p = 8; p < 16; ++p) {
      int row = p * NPI + i;
      float wv = rowdot_h(wb, t8, row - 384, kh ? 0.f : b_par[row]);
      vh[p] += wv * xi;
    }
  }
  __syncthreads();

  // ---- phase C: rows [768,1056) = b_h(16) + w_o(256) + b_o(16), 18 KB
  for (int idx = tid; idx < 288 * 16; idx += HEAD_T) {
    float2 v = wp2[768 * 16 + idx];
    buf[idx] = f16x2{(f16)v.x, (f16)v.y};
  }
  __syncthreads();

  float oh[16];
  #pragma unroll
  for (int p = 0; p < 16; ++p) {
    float bh = rowdot_h(wb, t8, p, kh ? 0.f : b_par[768 + p]);   // local row p
    float s = vh[p] + bh;
    s += __shfl_xor(s, 1, 64);
    oh[p] = ftanh(s);
  }

  #pragma unroll 2
  for (int o = 0; o < 16; ++o) {
    // b_o: local rows 272..288
    float macc = rowdot_h(wb, t8, 272 + o, kh ? 0.f : b_par[1040 + o]);
    #pragma unroll
    for (int p = 0; p < 16; ++p) {
      int grow = 784 + o * 16 + p;           // local 16 + o*16 + p
      float wv = rowdot_h(wb, t8, 16 + o * 16 + p, kh ? 0.f : b_par[grow]);
      macc += wv * oh[p];
    }
    macc += __shfl_xor(macc, 1, 64);
    if (!kh) {
      if (o < NOD) out[MEAN_OFF + m * NOD + o] = macc;
      else         out[STD_OFF + m * NOD + (o - NOD)] = fexpf_(macc);
    }
  }
}

// ---------------------------------------------------------------------------
extern "C" void kernel_launch(void* const* d_in, const int* in_sizes, int n_in,
                              void* d_out, int out_size, void* d_ws, size_t ws_size,
                              hipStream_t stream)
{
  const float* x      = (const float*)d_in[0];
  const float* hidden = (const float*)d_in[1];
  const float* w_ih   = (const float*)d_in[2];
  const float* w_hh   = (const float*)d_in[3];
  const float* b_ih   = (const float*)d_in[4];
  const float* b_hh   = (const float*)d_in[5];
  const float* w_lat  = (const float*)d_in[6];
  const float* b_lat  = (const float*)d_in[7];
  const float* w_par  = (const float*)d_in[8];
  const float* b_par  = (const float*)d_in[9];
  float* out = (float*)d_out;

  f16* gx  = (f16*)d_ws;                                  // 100,663,296 B
  f16* rnn = (f16*)((char*)d_ws + 100663296);             // 33,554,432 B

  k_gx  <<<dim3(1024, 4), 256, 0, stream>>>(x, w_ih, b_ih, gx);
  k_scan<<<NBATCH, 1024, 0, stream>>>(hidden, w_hh, b_hh, gx, rnn, out);
  k_head<<<512, HEAD_T, 0, stream>>>(x, w_lat, b_lat, w_par, b_par, rnn, out);
}

// Round 7
// 926.731 us; speedup vs baseline: 1.1583x; 1.1583x over previous
//
#include <hip/hip_runtime.h>
#include <cstdint>
#include <cstddef>

// Problem constants
#define NBATCH 128
#define NTIME  512
#define NIN    64
#define NHID   256
#define NG     768     // 3*H
#define NLAT   32
#define NPp    16      // P
#define NPI    48
#define NOD    8
#define NPAR   1056
#define MEAN_OFF 0
#define STD_OFF  524288      // B*T*OD
#define HT_OFF   1048576     // 2*B*T*OD

typedef _Float16 f16;
typedef _Float16 f16x2 __attribute__((ext_vector_type(2)));
typedef uint32_t u32;

static __device__ __forceinline__ f16x2 u2h(u32 u) {
  union { u32 u; f16x2 h; } x; x.u = u; return x.h;
}
static __device__ __forceinline__ u32 pkf(float a, float b) {
  union { f16x2 h; u32 u; } r; r.h = f16x2{(f16)a, (f16)b}; return r.u;
}
static __device__ __forceinline__ uint4 pack8(float4 a, float4 b) {
  uint4 r;
  r.x = pkf(a.x, a.y); r.y = pkf(a.z, a.w);
  r.z = pkf(b.x, b.y); r.w = pkf(b.z, b.w);
  return r;
}

static __device__ __forceinline__ float fdot2(f16x2 a, f16x2 b, float c) {
#if __has_builtin(__builtin_amdgcn_fdot2)
  return __builtin_amdgcn_fdot2(a, b, c, false);   // v_dot2_f32_f16
#else
  return c + (float)a.x * (float)b.x + (float)a.y * (float)b.y;
#endif
}
static __device__ __forceinline__ float fexp2(float x) {
#if __has_builtin(__builtin_amdgcn_exp2f)
  return __builtin_amdgcn_exp2f(x);
#else
  return exp2f(x);
#endif
}
static __device__ __forceinline__ float frcp(float x) {
#if __has_builtin(__builtin_amdgcn_rcpf)
  return __builtin_amdgcn_rcpf(x);
#else
  return 1.0f / x;
#endif
}
static __device__ __forceinline__ float fsigmoid(float x) {
  return frcp(1.0f + fexp2(-1.4426950408889634f * x));
}
static __device__ __forceinline__ float ftanh(float x) {
  return 1.0f - 2.0f * frcp(1.0f + fexp2(2.8853900817779268f * x));
}
static __device__ __forceinline__ float fexpf_(float x) {
  return fexp2(1.4426950408889634f * x);
}

// ---------------------------------------------------------------------------
// K1: gx[m, n] = sum_k x[m,k] * w_ih[n,k] + b_ih[n]   (M=65536, N=768, K=64)
// launch_bounds(256,1): under the empirically-fitted budget law
// (granted ~= 512/(2*min_waves_eu)), min=4 gave 64 regs -> acc spilled.
// ---------------------------------------------------------------------------
__global__ __launch_bounds__(256, 1) void k_gx(
    const float* __restrict__ x, const float* __restrict__ w_ih,
    const float* __restrict__ b_ih, f16* __restrict__ gx)
{
  __shared__ f16x2 xs[64 * 33];
  __shared__ f16x2 ws[192 * 33];
  __shared__ float bs[192];
  const int tid = threadIdx.x;
  const int m0 = blockIdx.x * 64;
  const int c0 = blockIdx.y * 192;
  const float2* x2 = (const float2*)x;
  const float2* w2 = (const float2*)w_ih;
  for (int idx = tid; idx < 64 * 32; idx += 256) {
    int r = idx >> 5, kk = idx & 31;
    float2 v = x2[(size_t)(m0 + r) * 32 + kk];
    xs[r * 33 + kk] = f16x2{(f16)v.x, (f16)v.y};
  }
  for (int idx = tid; idx < 192 * 32; idx += 256) {
    int r = idx >> 5, kk = idx & 31;
    float2 v = w2[(size_t)(c0 + r) * 32 + kk];
    ws[r * 33 + kk] = f16x2{(f16)v.x, (f16)v.y};
  }
  if (tid < 192) bs[tid] = b_ih[c0 + tid];
  __syncthreads();

  const int tc = tid & 15;
  const int tr = tid >> 4;
  float acc[4][12];
  #pragma unroll
  for (int j = 0; j < 4; ++j)
    #pragma unroll
    for (int i = 0; i < 12; ++i) acc[j][i] = 0.f;

  for (int kk = 0; kk < 32; ++kk) {
    f16x2 xa[4], wb[12];
    #pragma unroll
    for (int j = 0; j < 4; ++j) xa[j] = xs[(tr * 4 + j) * 33 + kk];
    #pragma unroll
    for (int i = 0; i < 12; ++i) wb[i] = ws[(tc * 12 + i) * 33 + kk];
    #pragma unroll
    for (int j = 0; j < 4; ++j)
      #pragma unroll
      for (int i = 0; i < 12; ++i) acc[j][i] = fdot2(xa[j], wb[i], acc[j][i]);
  }

  f16x2* g2 = (f16x2*)gx;
  #pragma unroll
  for (int j = 0; j < 4; ++j) {
    size_t row = (size_t)(m0 + tr * 4 + j);
    #pragma unroll
    for (int i2 = 0; i2 < 6; ++i2) {
      float a0 = acc[j][2 * i2]     + bs[tc * 12 + 2 * i2];
      float a1 = acc[j][2 * i2 + 1] + bs[tc * 12 + 2 * i2 + 1];
      g2[row * 384 + (size_t)(c0 / 2) + tc * 6 + i2] = f16x2{(f16)a0, (f16)a1};
    }
  }
}

// ---------------------------------------------------------------------------
// K2 v8: GRU scan. 512 threads, launch_bounds(512, 1): both candidate
// budget laws give a 256-VGPR budget (R1/R2/R6 fit granted =
// 512/(2*min_waves_eu): min 3->84, 2->128, 4->64). Thread pair (2u,2u+1)
// owns unit u (rows u, 256+u, 512+u), K-half per lane -> 48 named uint4
// = 192 f16x2 weight VGPRs + ~45 live overhead ~= 240 <= 256. 8-wave
// block @ ~250 regs = 122880 < 131072 regs/CU -> 1 block/CU, 2 waves/EU.
// K-reduce via shfl_xor(1); gates computed redundantly on both lanes;
// double-buffered h in LDS -> ONE barrier/step; h reads are 16 b128
// 2-way broadcasts (free per m136).
// ---------------------------------------------------------------------------
#define LDW16(W, row) { \
    const float4* p4 = (const float4*)(w_hh + (size_t)(row) * 256 + kh * 128); \
    float4 s0, s1; \
    s0 = p4[0];  s1 = p4[1];  W##0  = pack8(s0, s1); \
    s0 = p4[2];  s1 = p4[3];  W##1  = pack8(s0, s1); \
    s0 = p4[4];  s1 = p4[5];  W##2  = pack8(s0, s1); \
    s0 = p4[6];  s1 = p4[7];  W##3  = pack8(s0, s1); \
    s0 = p4[8];  s1 = p4[9];  W##4  = pack8(s0, s1); \
    s0 = p4[10]; s1 = p4[11]; W##5  = pack8(s0, s1); \
    s0 = p4[12]; s1 = p4[13]; W##6  = pack8(s0, s1); \
    s0 = p4[14]; s1 = p4[15]; W##7  = pack8(s0, s1); \
    s0 = p4[16]; s1 = p4[17]; W##8  = pack8(s0, s1); \
    s0 = p4[18]; s1 = p4[19]; W##9  = pack8(s0, s1); \
    s0 = p4[20]; s1 = p4[21]; W##10 = pack8(s0, s1); \
    s0 = p4[22]; s1 = p4[23]; W##11 = pack8(s0, s1); \
    s0 = p4[24]; s1 = p4[25]; W##12 = pack8(s0, s1); \
    s0 = p4[26]; s1 = p4[27]; W##13 = pack8(s0, s1); \
    s0 = p4[28]; s1 = p4[29]; W##14 = pack8(s0, s1); \
    s0 = p4[30]; s1 = p4[31]; W##15 = pack8(s0, s1); }

#define DOT4(Ri, Zi, Ni, i) { \
    uint4 hv = hb[i]; \
    f16x2 h0 = u2h(hv.x), h1 = u2h(hv.y), h2v = u2h(hv.z), h3 = u2h(hv.w); \
    a0 = fdot2(u2h(Ri.x), h0, a0); b0 = fdot2(u2h(Zi.x), h0, b0); d0 = fdot2(u2h(Ni.x), h0, d0); \
    a1 = fdot2(u2h(Ri.y), h1, a1); b1 = fdot2(u2h(Zi.y), h1, b1); d1 = fdot2(u2h(Ni.y), h1, d1); \
    a0 = fdot2(u2h(Ri.z), h2v, a0); b0 = fdot2(u2h(Zi.z), h2v, b0); d0 = fdot2(u2h(Ni.z), h2v, d0); \
    a1 = fdot2(u2h(Ri.w), h3, a1); b1 = fdot2(u2h(Zi.w), h3, b1); d1 = fdot2(u2h(Ni.w), h3, d1); }

__global__ __launch_bounds__(512, 1) void k_scan(
    const float* __restrict__ hidden, const float* __restrict__ w_hh,
    const float* __restrict__ b_hh, const f16* __restrict__ gx,
    f16* __restrict__ rnn, float* __restrict__ out)
{
  __shared__ __align__(16) f16 hbuf[2][256];   // double-buffered h (f16)
  const int tid = threadIdx.x;
  const int b = blockIdx.x;
  const int u  = tid >> 1;       // unit 0..255
  const int kh = tid & 1;        // K-half 0/1

  // --- stationary weights: 48 named uint4 (192 f16x2) ---
  uint4 R0,R1,R2,R3,R4,R5,R6,R7,R8,R9,R10,R11,R12,R13,R14,R15;
  uint4 Z0,Z1,Z2,Z3,Z4,Z5,Z6,Z7,Z8,Z9,Z10,Z11,Z12,Z13,Z14,Z15;
  uint4 N0,N1,N2,N3,N4,N5,N6,N7,N8,N9,N10,N11,N12,N13,N14,N15;
  LDW16(R, u);
  LDW16(Z, 256 + u);
  LDW16(N, 512 + u);

  const float br = b_hh[u];
  const float bz = b_hh[256 + u];
  const float bn = b_hh[512 + u];
  float hprev = hidden[b * 256 + u];
  if (!kh) hbuf[0][u] = (f16)hprev;

  const f16* gp = gx + (size_t)b * NTIME * NG;
  f16 c_r = gp[u], c_z = gp[256 + u], c_n = gp[512 + u];
  f16* rnn_p = rnn + (size_t)b * NTIME * NHID + u;
  __syncthreads();

  for (int t = 0; t < NTIME; ++t) {
    // prefetch gx for t+1 (covers the whole dot phase)
    const int tp = (t + 1 < NTIME) ? (t + 1) : (NTIME - 1);
    const f16* gq = gp + (size_t)tp * NG;
    f16 q_r = gq[u], q_z = gq[256 + u], q_n = gq[512 + u];

    // --- dot phase: 192 dot2; h via 2-way-broadcast b128 LDS reads
    const uint4* hb = (const uint4*)hbuf[t & 1] + kh * 16;
    float a0 = 0.f, a1 = 0.f, b0 = 0.f, b1 = 0.f, d0 = 0.f, d1 = 0.f;
    DOT4(R0,  Z0,  N0,  0)
    DOT4(R1,  Z1,  N1,  1)
    DOT4(R2,  Z2,  N2,  2)
    DOT4(R3,  Z3,  N3,  3)
    DOT4(R4,  Z4,  N4,  4)
    DOT4(R5,  Z5,  N5,  5)
    DOT4(R6,  Z6,  N6,  6)
    DOT4(R7,  Z7,  N7,  7)
    DOT4(R8,  Z8,  N8,  8)
    DOT4(R9,  Z9,  N9,  9)
    DOT4(R10, Z10, N10, 10)
    DOT4(R11, Z11, N11, 11)
    DOT4(R12, Z12, N12, 12)
    DOT4(R13, Z13, N13, 13)
    DOT4(R14, Z14, N14, 14)
    DOT4(R15, Z15, N15, 15)

    float sr = a0 + a1, sz = b0 + b1, sn = d0 + d1;
    sr += __shfl_xor(sr, 1, 64);     // K-half combine within the pair
    sz += __shfl_xor(sz, 1, 64);
    sn += __shfl_xor(sn, 1, 64);

    // --- gates (both lanes compute identically; no divergence)
    float r_ = fsigmoid(sr + br + (float)c_r);
    float z_ = fsigmoid(sz + bz + (float)c_z);
    float n_ = ftanh((float)c_n + r_ * (sn + bn));
    hprev = (1.0f - z_) * n_ + z_ * hprev;

    if (!kh) {
      hbuf[(t + 1) & 1][u] = (f16)hprev;
      rnn_p[(size_t)t * NHID] = (f16)hprev;
    }
    c_r = q_r; c_z = q_z; c_n = q_n;
    __syncthreads();
  }
  if (!kh) out[HT_OFF + b * 256 + u] = hprev;
}

// ---------------------------------------------------------------------------
// K3 helper: half-row dot (16 of 32 latents; caller pre-offset wb by kh*2
// uint4 and t8 = te2 + kh*8). init carries b_par[row] on kh==0 only.
// ---------------------------------------------------------------------------
static __device__ __forceinline__ float rowdot_h(const uint4* __restrict__ wb,
                                                 const f16x2* __restrict__ t8,
                                                 int r, float init)
{
  uint4 v0 = wb[r * 4];
  uint4 v1 = wb[r * 4 + 1];
  float a0 = init, a1 = 0.f, a2 = 0.f, a3 = 0.f;
  a0 = fdot2(u2h(v0.x), t8[0], a0);
  a1 = fdot2(u2h(v0.y), t8[1], a1);
  a2 = fdot2(u2h(v0.z), t8[2], a2);
  a3 = fdot2(u2h(v0.w), t8[3], a3);
  a0 = fdot2(u2h(v1.x), t8[4], a0);
  a1 = fdot2(u2h(v1.y), t8[5], a1);
  a2 = fdot2(u2h(v1.z), t8[6], a2);
  a3 = fdot2(u2h(v1.w), t8[7], a3);
  return (a0 + a1) + (a2 + a3);
}

// ---------------------------------------------------------------------------
// K3 v5: head, 2 threads per (b,t) row. launch_bounds(256,1) -> full reg
// budget so te[]/vh[]/oh[] stay resident.
// ---------------------------------------------------------------------------
#define HEAD_T 256
__global__ __launch_bounds__(HEAD_T, 1) void k_head(
    const float* __restrict__ x, const float* __restrict__ w_lat,
    const float* __restrict__ b_lat, const float* __restrict__ w_par,
    const float* __restrict__ b_par, const f16* __restrict__ rnn,
    float* __restrict__ out)
{
  __shared__ __align__(16) f16x2 buf[384 * 16];   // 24 KB chunk buffer
  const int tid = threadIdx.x;
  const int j = tid >> 1, kh = tid & 1;
  const size_t m = (size_t)blockIdx.x * (HEAD_T / 2) + j;

  // ---- phase A: te = b_lat + w_lat @ h  (K split by kh)
  const float2* wl2 = (const float2*)w_lat;
  for (int idx = tid; idx < 32 * 128; idx += HEAD_T) {
    float2 v = wl2[idx];
    buf[idx] = f16x2{(f16)v.x, (f16)v.y};
  }
  __syncthreads();

  float te[32];
  #pragma unroll
  for (int c = 0; c < 32; ++c) te[c] = kh ? 0.f : b_lat[c];
  const uint4* hrow = (const uint4*)(rnn + m * NHID) + kh * 16;
  const uint4* wl4 = (const uint4*)buf;    // 32 uint4 per 256-wide row
  #pragma unroll 2
  for (int c4 = 0; c4 < 16; ++c4) {
    uint4 hv = hrow[c4];
    f16x2 hx0 = u2h(hv.x), hx1 = u2h(hv.y), hx2 = u2h(hv.z), hx3 = u2h(hv.w);
    #pragma unroll
    for (int c = 0; c < 32; ++c) {
      uint4 wv = wl4[c * 32 + kh * 16 + c4];
      te[c] = fdot2(u2h(wv.x), hx0, te[c]);
      te[c] = fdot2(u2h(wv.y), hx1, te[c]);
      te[c] = fdot2(u2h(wv.z), hx2, te[c]);
      te[c] = fdot2(u2h(wv.w), hx3, te[c]);
    }
  }
  #pragma unroll
  for (int c = 0; c < 32; ++c) te[c] += __shfl_xor(te[c], 1, 64);
  f16x2 te2[16];
  #pragma unroll
  for (int k = 0; k < 16; ++k) te2[k] = f16x2{(f16)te[2 * k], (f16)te[2 * k + 1]};
  const f16x2* t8 = te2 + kh * 8;
  __syncthreads();

  const float2* wp2 = (const float2*)w_par;   // 16 float2 per 32-wide row
  const uint4* wb = ((const uint4*)buf) + kh * 2;
  const float* xrow = x + m * NIN;
  float vh[16];
  #pragma unroll
  for (int p = 0; p < 16; ++p) vh[p] = 0.f;

  // ---- phase B0: w_h rows [0,384)  (p = 0..7)
  for (int idx = tid; idx < 384 * 16; idx += HEAD_T) {
    float2 v = wp2[idx];
    buf[idx] = f16x2{(f16)v.x, (f16)v.y};
  }
  __syncthreads();
  for (int i = 0; i < NPI; ++i) {
    float xi = xrow[i];
    #pragma unroll
    for (int p = 0; p < 8; ++p) {
      int row = p * NPI + i;
      float wv = rowdot_h(wb, t8, row, kh ? 0.f : b_par[row]);
      vh[p] += wv * xi;
    }
  }
  __syncthreads();

  // ---- phase B1: w_h rows [384,768)  (p = 8..15)
  for (int idx = tid; idx < 384 * 16; idx += HEAD_T) {
    float2 v = wp2[384 * 16 + idx];
    buf[idx] = f16x2{(f16)v.x, (f16)v.y};
  }
  __syncthreads();
  for (int i = 0; i < NPI; ++i) {
    float xi = xrow[i];
    #pragma unroll
    for (int p = 8; p < 16; ++p) {
      int row = p * NPI + i;
      float wv = rowdot_h(wb, t8, row - 384, kh ? 0.f : b_par[row]);
      vh[p] += wv * xi;
    }
  }
  __syncthreads();

  // ---- phase C: rows [768,1056) = b_h(16) + w_o(256) + b_o(16), 18 KB
  for (int idx = tid; idx < 288 * 16; idx += HEAD_T) {
    float2 v = wp2[768 * 16 + idx];
    buf[idx] = f16x2{(f16)v.x, (f16)v.y};
  }
  __syncthreads();

  float oh[16];
  #pragma unroll
  for (int p = 0; p < 16; ++p) {
    float bh = rowdot_h(wb, t8, p, kh ? 0.f : b_par[768 + p]);   // local row p
    float s = vh[p] + bh;
    s += __shfl_xor(s, 1, 64);
    oh[p] = ftanh(s);
  }

  #pragma unroll 2
  for (int o = 0; o < 16; ++o) {
    // b_o: local rows 272..288
    float macc = rowdot_h(wb, t8, 272 + o, kh ? 0.f : b_par[1040 + o]);
    #pragma unroll
    for (int p = 0; p < 16; ++p) {
      int grow = 784 + o * 16 + p;           // local 16 + o*16 + p
      float wv = rowdot_h(wb, t8, 16 + o * 16 + p, kh ? 0.f : b_par[grow]);
      macc += wv * oh[p];
    }
    macc += __shfl_xor(macc, 1, 64);
    if (!kh) {
      if (o < NOD) out[MEAN_OFF + m * NOD + o] = macc;
      else         out[STD_OFF + m * NOD + (o - NOD)] = fexpf_(macc);
    }
  }
}

// ---------------------------------------------------------------------------
extern "C" void kernel_launch(void* const* d_in, const int* in_sizes, int n_in,
                              void* d_out, int out_size, void* d_ws, size_t ws_size,
                              hipStream_t stream)
{
  const float* x      = (const float*)d_in[0];
  const float* hidden = (const float*)d_in[1];
  const float* w_ih   = (const float*)d_in[2];
  const float* w_hh   = (const float*)d_in[3];
  const float* b_ih   = (const float*)d_in[4];
  const float* b_hh   = (const float*)d_in[5];
  const float* w_lat  = (const float*)d_in[6];
  const float* b_lat  = (const float*)d_in[7];
  const float* w_par  = (const float*)d_in[8];
  const float* b_par  = (const float*)d_in[9];
  float* out = (float*)d_out;

  f16* gx  = (f16*)d_ws;                                  // 100,663,296 B
  f16* rnn = (f16*)((char*)d_ws + 100663296);             // 33,554,432 B

  k_gx  <<<dim3(1024, 4), 256, 0, stream>>>(x, w_ih, b_ih, gx);
  k_scan<<<NBATCH, 512, 0, stream>>>(hidden, w_hh, b_hh, gx, rnn, out);
  k_head<<<512, HEAD_T, 0, stream>>>(x, w_lat, b_lat, w_par, b_par, rnn, out);
}

// Round 8
// 901.906 us; speedup vs baseline: 1.1902x; 1.0275x over previous
//
#include <hip/hip_runtime.h>
#include <cstdint>
#include <cstddef>

// Problem constants
#define NBATCH 128
#define NTIME  512
#define NIN    64
#define NHID   256
#define NG     768     // 3*H
#define NLAT   32
#define NPp    16      // P
#define NPI    48
#define NOD    8
#define NPAR   1056
#define MEAN_OFF 0
#define STD_OFF  524288      // B*T*OD
#define HT_OFF   1048576     // 2*B*T*OD

typedef _Float16 f16;
typedef _Float16 f16x2 __attribute__((ext_vector_type(2)));
typedef uint32_t u32;

static __device__ __forceinline__ f16x2 u2h(u32 u) {
  union { u32 u; f16x2 h; } x; x.u = u; return x.h;
}
static __device__ __forceinline__ u32 pkf(float a, float b) {
  union { f16x2 h; u32 u; } r; r.h = f16x2{(f16)a, (f16)b}; return r.u;
}
static __device__ __forceinline__ uint4 pack8(float4 a, float4 b) {
  uint4 r;
  r.x = pkf(a.x, a.y); r.y = pkf(a.z, a.w);
  r.z = pkf(b.x, b.y); r.w = pkf(b.z, b.w);
  return r;
}

static __device__ __forceinline__ float fdot2(f16x2 a, f16x2 b, float c) {
#if __has_builtin(__builtin_amdgcn_fdot2)
  return __builtin_amdgcn_fdot2(a, b, c, false);   // v_dot2_f32_f16
#else
  return c + (float)a.x * (float)b.x + (float)a.y * (float)b.y;
#endif
}
static __device__ __forceinline__ float fexp2(float x) {
#if __has_builtin(__builtin_amdgcn_exp2f)
  return __builtin_amdgcn_exp2f(x);
#else
  return exp2f(x);
#endif
}
static __device__ __forceinline__ float frcp(float x) {
#if __has_builtin(__builtin_amdgcn_rcpf)
  return __builtin_amdgcn_rcpf(x);
#else
  return 1.0f / x;
#endif
}
static __device__ __forceinline__ float fsigmoid(float x) {
  return frcp(1.0f + fexp2(-1.4426950408889634f * x));
}
static __device__ __forceinline__ float ftanh(float x) {
  return 1.0f - 2.0f * frcp(1.0f + fexp2(2.8853900817779268f * x));
}
static __device__ __forceinline__ float fexpf_(float x) {
  return fexp2(1.4426950408889634f * x);
}

// ---------------------------------------------------------------------------
// K1: gx[m, n] = sum_k x[m,k] * w_ih[n,k] + b_ih[n]   (M=65536, N=768, K=64)
// ---------------------------------------------------------------------------
__global__ __launch_bounds__(256, 1) void k_gx(
    const float* __restrict__ x, const float* __restrict__ w_ih,
    const float* __restrict__ b_ih, f16* __restrict__ gx)
{
  __shared__ f16x2 xs[64 * 33];
  __shared__ f16x2 ws[192 * 33];
  __shared__ float bs[192];
  const int tid = threadIdx.x;
  const int m0 = blockIdx.x * 64;
  const int c0 = blockIdx.y * 192;
  const float2* x2 = (const float2*)x;
  const float2* w2 = (const float2*)w_ih;
  for (int idx = tid; idx < 64 * 32; idx += 256) {
    int r = idx >> 5, kk = idx & 31;
    float2 v = x2[(size_t)(m0 + r) * 32 + kk];
    xs[r * 33 + kk] = f16x2{(f16)v.x, (f16)v.y};
  }
  for (int idx = tid; idx < 192 * 32; idx += 256) {
    int r = idx >> 5, kk = idx & 31;
    float2 v = w2[(size_t)(c0 + r) * 32 + kk];
    ws[r * 33 + kk] = f16x2{(f16)v.x, (f16)v.y};
  }
  if (tid < 192) bs[tid] = b_ih[c0 + tid];
  __syncthreads();

  const int tc = tid & 15;
  const int tr = tid >> 4;
  float acc[4][12];
  #pragma unroll
  for (int j = 0; j < 4; ++j)
    #pragma unroll
    for (int i = 0; i < 12; ++i) acc[j][i] = 0.f;

  for (int kk = 0; kk < 32; ++kk) {
    f16x2 xa[4], wb[12];
    #pragma unroll
    for (int j = 0; j < 4; ++j) xa[j] = xs[(tr * 4 + j) * 33 + kk];
    #pragma unroll
    for (int i = 0; i < 12; ++i) wb[i] = ws[(tc * 12 + i) * 33 + kk];
    #pragma unroll
    for (int j = 0; j < 4; ++j)
      #pragma unroll
      for (int i = 0; i < 12; ++i) acc[j][i] = fdot2(xa[j], wb[i], acc[j][i]);
  }

  f16x2* g2 = (f16x2*)gx;
  #pragma unroll
  for (int j = 0; j < 4; ++j) {
    size_t row = (size_t)(m0 + tr * 4 + j);
    #pragma unroll
    for (int i2 = 0; i2 < 6; ++i2) {
      float a0 = acc[j][2 * i2]     + bs[tc * 12 + 2 * i2];
      float a1 = acc[j][2 * i2 + 1] + bs[tc * 12 + 2 * i2 + 1];
      g2[row * 384 + (size_t)(c0 / 2) + tc * 6 + i2] = f16x2{(f16)a0, (f16)a1};
    }
  }
}

// ---------------------------------------------------------------------------
// K2 v9: GRU scan, R7 structure + amdgpu_num_vgpr(256).
// Budget law fitted over R1-R7: granted = 512/(2*max(min_waves, block_waves))
// -> no launch config can reach the 237 regs this design needs; the weight
// array spilled in EVERY round (WRITE_SIZE excess ~= 50 MB footprint; 25.8 GB
// of per-step re-reads at ~41 TB/s L2/L3 = the invariant ~620 us).
// amdgpu_num_vgpr(256) pins the allocator's VGPR limit directly, bypassing
// the waves-based budget. 8 waves x 256 regs = the full 512-reg/lane file
// (m08: spill starts at 512) -> 1 block/CU, 2 waves/EU.
// ---------------------------------------------------------------------------
#define LDW16(W, row) { \
    const float4* p4 = (const float4*)(w_hh + (size_t)(row) * 256 + kh * 128); \
    float4 s0, s1; \
    s0 = p4[0];  s1 = p4[1];  W##0  = pack8(s0, s1); \
    s0 = p4[2];  s1 = p4[3];  W##1  = pack8(s0, s1); \
    s0 = p4[4];  s1 = p4[5];  W##2  = pack8(s0, s1); \
    s0 = p4[6];  s1 = p4[7];  W##3  = pack8(s0, s1); \
    s0 = p4[8];  s1 = p4[9];  W##4  = pack8(s0, s1); \
    s0 = p4[10]; s1 = p4[11]; W##5  = pack8(s0, s1); \
    s0 = p4[12]; s1 = p4[13]; W##6  = pack8(s0, s1); \
    s0 = p4[14]; s1 = p4[15]; W##7  = pack8(s0, s1); \
    s0 = p4[16]; s1 = p4[17]; W##8  = pack8(s0, s1); \
    s0 = p4[18]; s1 = p4[19]; W##9  = pack8(s0, s1); \
    s0 = p4[20]; s1 = p4[21]; W##10 = pack8(s0, s1); \
    s0 = p4[22]; s1 = p4[23]; W##11 = pack8(s0, s1); \
    s0 = p4[24]; s1 = p4[25]; W##12 = pack8(s0, s1); \
    s0 = p4[26]; s1 = p4[27]; W##13 = pack8(s0, s1); \
    s0 = p4[28]; s1 = p4[29]; W##14 = pack8(s0, s1); \
    s0 = p4[30]; s1 = p4[31]; W##15 = pack8(s0, s1); }

#define DOT4(Ri, Zi, Ni, i) { \
    uint4 hv = hb[i]; \
    f16x2 h0 = u2h(hv.x), h1 = u2h(hv.y), h2v = u2h(hv.z), h3 = u2h(hv.w); \
    a0 = fdot2(u2h(Ri.x), h0, a0); b0 = fdot2(u2h(Zi.x), h0, b0); d0 = fdot2(u2h(Ni.x), h0, d0); \
    a1 = fdot2(u2h(Ri.y), h1, a1); b1 = fdot2(u2h(Zi.y), h1, b1); d1 = fdot2(u2h(Ni.y), h1, d1); \
    a0 = fdot2(u2h(Ri.z), h2v, a0); b0 = fdot2(u2h(Zi.z), h2v, b0); d0 = fdot2(u2h(Ni.z), h2v, d0); \
    a1 = fdot2(u2h(Ri.w), h3, a1); b1 = fdot2(u2h(Zi.w), h3, b1); d1 = fdot2(u2h(Ni.w), h3, d1); }

__global__
__attribute__((amdgpu_flat_work_group_size(512, 512)))
__attribute__((amdgpu_waves_per_eu(2)))
__attribute__((amdgpu_num_vgpr(256)))
void k_scan(
    const float* __restrict__ hidden, const float* __restrict__ w_hh,
    const float* __restrict__ b_hh, const f16* __restrict__ gx,
    f16* __restrict__ rnn, float* __restrict__ out)
{
  __shared__ __align__(16) f16 hbuf[2][256];   // double-buffered h (f16)
  const int tid = threadIdx.x;
  const int b = blockIdx.x;
  const int u  = tid >> 1;       // unit 0..255
  const int kh = tid & 1;        // K-half 0/1

  // --- stationary weights: 48 named uint4 (192 f16x2) ---
  uint4 R0,R1,R2,R3,R4,R5,R6,R7,R8,R9,R10,R11,R12,R13,R14,R15;
  uint4 Z0,Z1,Z2,Z3,Z4,Z5,Z6,Z7,Z8,Z9,Z10,Z11,Z12,Z13,Z14,Z15;
  uint4 N0,N1,N2,N3,N4,N5,N6,N7,N8,N9,N10,N11,N12,N13,N14,N15;
  LDW16(R, u);
  LDW16(Z, 256 + u);
  LDW16(N, 512 + u);

  const float br = b_hh[u];
  const float bz = b_hh[256 + u];
  const float bn = b_hh[512 + u];
  float hprev = hidden[b * 256 + u];
  if (!kh) hbuf[0][u] = (f16)hprev;

  const f16* gp = gx + (size_t)b * NTIME * NG;
  f16 c_r = gp[u], c_z = gp[256 + u], c_n = gp[512 + u];
  f16* rnn_p = rnn + (size_t)b * NTIME * NHID + u;
  __syncthreads();

  for (int t = 0; t < NTIME; ++t) {
    // prefetch gx for t+1 (covers the whole dot phase)
    const int tp = (t + 1 < NTIME) ? (t + 1) : (NTIME - 1);
    const f16* gq = gp + (size_t)tp * NG;
    f16 q_r = gq[u], q_z = gq[256 + u], q_n = gq[512 + u];

    // --- dot phase: 192 dot2; h via 2-way-broadcast b128 LDS reads
    const uint4* hb = (const uint4*)hbuf[t & 1] + kh * 16;
    float a0 = 0.f, a1 = 0.f, b0 = 0.f, b1 = 0.f, d0 = 0.f, d1 = 0.f;
    DOT4(R0,  Z0,  N0,  0)
    DOT4(R1,  Z1,  N1,  1)
    DOT4(R2,  Z2,  N2,  2)
    DOT4(R3,  Z3,  N3,  3)
    DOT4(R4,  Z4,  N4,  4)
    DOT4(R5,  Z5,  N5,  5)
    DOT4(R6,  Z6,  N6,  6)
    DOT4(R7,  Z7,  N7,  7)
    DOT4(R8,  Z8,  N8,  8)
    DOT4(R9,  Z9,  N9,  9)
    DOT4(R10, Z10, N10, 10)
    DOT4(R11, Z11, N11, 11)
    DOT4(R12, Z12, N12, 12)
    DOT4(R13, Z13, N13, 13)
    DOT4(R14, Z14, N14, 14)
    DOT4(R15, Z15, N15, 15)

    float sr = a0 + a1, sz = b0 + b1, sn = d0 + d1;
    sr += __shfl_xor(sr, 1, 64);     // K-half combine within the pair
    sz += __shfl_xor(sz, 1, 64);
    sn += __shfl_xor(sn, 1, 64);

    // --- gates (both lanes compute identically; no divergence)
    float r_ = fsigmoid(sr + br + (float)c_r);
    float z_ = fsigmoid(sz + bz + (float)c_z);
    float n_ = ftanh((float)c_n + r_ * (sn + bn));
    hprev = (1.0f - z_) * n_ + z_ * hprev;

    if (!kh) {
      hbuf[(t + 1) & 1][u] = (f16)hprev;
      rnn_p[(size_t)t * NHID] = (f16)hprev;
    }
    c_r = q_r; c_z = q_z; c_n = q_n;
    __syncthreads();
  }
  if (!kh) out[HT_OFF + b * 256 + u] = hprev;
}

// ---------------------------------------------------------------------------
// K3 helper: half-row dot (16 of 32 latents; caller pre-offset wb by kh*2
// uint4 and t8 = te2 + kh*8). init carries b_par[row] on kh==0 only.
// ---------------------------------------------------------------------------
static __device__ __forceinline__ float rowdot_h(const uint4* __restrict__ wb,
                                                 const f16x2* __restrict__ t8,
                                                 int r, float init)
{
  uint4 v0 = wb[r * 4];
  uint4 v1 = wb[r * 4 + 1];
  float a0 = init, a1 = 0.f, a2 = 0.f, a3 = 0.f;
  a0 = fdot2(u2h(v0.x), t8[0], a0);
  a1 = fdot2(u2h(v0.y), t8[1], a1);
  a2 = fdot2(u2h(v0.z), t8[2], a2);
  a3 = fdot2(u2h(v0.w), t8[3], a3);
  a0 = fdot2(u2h(v1.x), t8[4], a0);
  a1 = fdot2(u2h(v1.y), t8[5], a1);
  a2 = fdot2(u2h(v1.z), t8[6], a2);
  a3 = fdot2(u2h(v1.w), t8[7], a3);
  return (a0 + a1) + (a2 + a3);
}

// ---------------------------------------------------------------------------
// K3 v5: head, 2 threads per (b,t) row. launch_bounds(256,1) -> full reg
// budget so te[]/vh[]/oh[] stay resident.
// ---------------------------------------------------------------------------
#define HEAD_T 256
__global__ __launch_bounds__(HEAD_T, 1) void k_head(
    const float* __restrict__ x, const float* __restrict__ w_lat,
    const float* __restrict__ b_lat, const float* __restrict__ w_par,
    const float* __restrict__ b_par, const f16* __restrict__ rnn,
    float* __restrict__ out)
{
  __shared__ __align__(16) f16x2 buf[384 * 16];   // 24 KB chunk buffer
  const int tid = threadIdx.x;
  const int j = tid >> 1, kh = tid & 1;
  const size_t m = (size_t)blockIdx.x * (HEAD_T / 2) + j;

  // ---- phase A: te = b_lat + w_lat @ h  (K split by kh)
  const float2* wl2 = (const float2*)w_lat;
  for (int idx = tid; idx < 32 * 128; idx += HEAD_T) {
    float2 v = wl2[idx];
    buf[idx] = f16x2{(f16)v.x, (f16)v.y};
  }
  __syncthreads();

  float te[32];
  #pragma unroll
  for (int c = 0; c < 32; ++c) te[c] = kh ? 0.f : b_lat[c];
  const uint4* hrow = (const uint4*)(rnn + m * NHID) + kh * 16;
  const uint4* wl4 = (const uint4*)buf;    // 32 uint4 per 256-wide row
  #pragma unroll 2
  for (int c4 = 0; c4 < 16; ++c4) {
    uint4 hv = hrow[c4];
    f16x2 hx0 = u2h(hv.x), hx1 = u2h(hv.y), hx2 = u2h(hv.z), hx3 = u2h(hv.w);
    #pragma unroll
    for (int c = 0; c < 32; ++c) {
      uint4 wv = wl4[c * 32 + kh * 16 + c4];
      te[c] = fdot2(u2h(wv.x), hx0, te[c]);
      te[c] = fdot2(u2h(wv.y), hx1, te[c]);
      te[c] = fdot2(u2h(wv.z), hx2, te[c]);
      te[c] = fdot2(u2h(wv.w), hx3, te[c]);
    }
  }
  #pragma unroll
  for (int c = 0; c < 32; ++c) te[c] += __shfl_xor(te[c], 1, 64);
  f16x2 te2[16];
  #pragma unroll
  for (int k = 0; k < 16; ++k) te2[k] = f16x2{(f16)te[2 * k], (f16)te[2 * k + 1]};
  const f16x2* t8 = te2 + kh * 8;
  __syncthreads();

  const float2* wp2 = (const float2*)w_par;   // 16 float2 per 32-wide row
  const uint4* wb = ((const uint4*)buf) + kh * 2;
  const float* xrow = x + m * NIN;
  float vh[16];
  #pragma unroll
  for (int p = 0; p < 16; ++p) vh[p] = 0.f;

  // ---- phase B0: w_h rows [0,384)  (p = 0..7)
  for (int idx = tid; idx < 384 * 16; idx += HEAD_T) {
    float2 v = wp2[idx];
    buf[idx] = f16x2{(f16)v.x, (f16)v.y};
  }
  __syncthreads();
  for (int i = 0; i < NPI; ++i) {
    float xi = xrow[i];
    #pragma unroll
    for (int p = 0; p < 8; ++p) {
      int row = p * NPI + i;
      float wv = rowdot_h(wb, t8, row, kh ? 0.f : b_par[row]);
      vh[p] += wv * xi;
    }
  }
  __syncthreads();

  // ---- phase B1: w_h rows [384,768)  (p = 8..15)
  for (int idx = tid; idx < 384 * 16; idx += HEAD_T) {
    float2 v = wp2[384 * 16 + idx];
    buf[idx] = f16x2{(f16)v.x, (f16)v.y};
  }
  __syncthreads();
  for (int i = 0; i < NPI; ++i) {
    float xi = xrow[i];
    #pragma unroll
    for (int p = 8; p < 16; ++p) {
      int row = p * NPI + i;
      float wv = rowdot_h(wb, t8, row - 384, kh ? 0.f : b_par[row]);
      vh[p] += wv * xi;
    }
  }
  __syncthreads();

  // ---- phase C: rows [768,1056) = b_h(16) + w_o(256) + b_o(16), 18 KB
  for (int idx = tid; idx < 288 * 16; idx += HEAD_T) {
    float2 v = wp2[768 * 16 + idx];
    buf[idx] = f16x2{(f16)v.x, (f16)v.y};
  }
  __syncthreads();

  float oh[16];
  #pragma unroll
  for (int p = 0; p < 16; ++p) {
    float bh = rowdot_h(wb, t8, p, kh ? 0.f : b_par[768 + p]);   // local row p
    float s = vh[p] + bh;
    s += __shfl_xor(s, 1, 64);
    oh[p] = ftanh(s);
  }

  #pragma unroll 2
  for (int o = 0; o < 16; ++o) {
    // b_o: local rows 272..288
    float macc = rowdot_h(wb, t8, 272 + o, kh ? 0.f : b_par[1040 + o]);
    #pragma unroll
    for (int p = 0; p < 16; ++p) {
      int grow = 784 + o * 16 + p;           // local 16 + o*16 + p
      float wv = rowdot_h(wb, t8, 16 + o * 16 + p, kh ? 0.f : b_par[grow]);
      macc += wv * oh[p];
    }
    macc += __shfl_xor(macc, 1, 64);
    if (!kh) {
      if (o < NOD) out[MEAN_OFF + m * NOD + o] = macc;
      else         out[STD_OFF + m * NOD + (o - NOD)] = fexpf_(macc);
    }
  }
}

// ---------------------------------------------------------------------------
extern "C" void kernel_launch(void* const* d_in, const int* in_sizes, int n_in,
                              void* d_out, int out_size, void* d_ws, size_t ws_size,
                              hipStream_t stream)
{
  const float* x      = (const float*)d_in[0];
  const float* hidden = (const float*)d_in[1];
  const float* w_ih   = (const float*)d_in[2];
  const float* w_hh   = (const float*)d_in[3];
  const float* b_ih   = (const float*)d_in[4];
  const float* b_hh   = (const float*)d_in[5];
  const float* w_lat  = (const float*)d_in[6];
  const float* b_lat  = (const float*)d_in[7];
  const float* w_par  = (const float*)d_in[8];
  const float* b_par  = (const float*)d_in[9];
  float* out = (float*)d_out;

  f16* gx  = (f16*)d_ws;                                  // 100,663,296 B
  f16* rnn = (f16*)((char*)d_ws + 100663296);             // 33,554,432 B

  k_gx  <<<dim3(1024, 4), 256, 0, stream>>>(x, w_ih, b_ih, gx);
  k_scan<<<NBATCH, 512, 0, stream>>>(hidden, w_hh, b_hh, gx, rnn, out);
  k_head<<<512, HEAD_T, 0, stream>>>(x, w_lat, b_lat, w_par, b_par, rnn, out);
}